// Round 17
// baseline (85.904 us; speedup 1.0000x reference)
//
#include <hip/hip_runtime.h>
#include <hip/hip_bf16.h>

// Problem sizes (fixed by reference)
#define B_   4
#define T_   2048
#define D_   512
#define H_   8
#define DH_  64
#define BT_  (B_*T_)          // 8192
#define N3D_ (3*D_)           // 1536

typedef __bf16  bf16x8 __attribute__((ext_vector_type(8)));
typedef float   f32x4  __attribute__((ext_vector_type(4)));
typedef short   short8 __attribute__((ext_vector_type(8)));
typedef unsigned short u16;

// exp2 fast path: fold log2(e) into the Q scale so softmax uses v_exp_f32.
#if defined(__has_builtin)
#if __has_builtin(__builtin_amdgcn_exp2f)
#define EXP2_OK 1
#endif
#endif
#ifndef EXP2_OK
#define EXP2_OK 0
#endif

#if EXP2_OK
#define QSCALE_F (0.125f * 1.44269504088896340736f)
static __device__ __forceinline__ float fastexp(float x) { return __builtin_amdgcn_exp2f(x); }
#else
#define QSCALE_F (0.125f)
static __device__ __forceinline__ float fastexp(float x) { return __expf(x); }
#endif

static __device__ __forceinline__ f32x4 fzero() { f32x4 z = {0.f,0.f,0.f,0.f}; return z; }

static __device__ __forceinline__ f32x4 mfma16(short8 a, short8 b, f32x4 c) {
  return __builtin_amdgcn_mfma_f32_16x16x32_bf16(
      __builtin_bit_cast(bf16x8, a), __builtin_bit_cast(bf16x8, b), c, 0, 0, 0);
}

// XOR swizzle for [row][128B] LDS tiles (read side). Content is written
// pre-swizzled via the global SOURCE address (rule 21: linear DMA dest +
// inverse-swizzled source + swizzled read).
static __device__ __forceinline__ int swz(int byteoff) {
  return byteoff ^ (((byteoff >> 7) & 7) << 4);
}

static __device__ __forceinline__ u16 bf16bits(float f) {
  __hip_bfloat16 h = __float2bfloat16(f);
  return *reinterpret_cast<u16*>(&h);
}

// async global->LDS DMA, 16B per lane. lds dest must be wave-uniform base
// (HW writes base + lane*16); global src is per-lane.
static __device__ __forceinline__ void gld_lds16(const void* g, void* l) {
  __builtin_amdgcn_global_load_lds(
      (const __attribute__((address_space(1))) void*)g,
      (__attribute__((address_space(3))) void*)l, 16, 0, 0);
}

// ---------------------------------------------------------------------------
// Kernel 1 (fused prep, r13): blocks [0,768): x -> bf16 (vectorized x8);
// blocks [768,960): wqkv LDS-tile transpose; [960,1024): wout transpose.
// ---------------------------------------------------------------------------
#define XBLKS 768
__global__ __launch_bounds__(256) void prep_kernel(
    const float* __restrict__ x, const float* __restrict__ wqkv,
    const float* __restrict__ wout,
    u16* __restrict__ xb, u16* __restrict__ wqkvT, u16* __restrict__ woutT) {
  __shared__ u16 lt[64 * 72];  // 64x64 bf16 tile, padded row stride 72
  const int tid = threadIdx.x;
  const int blk = blockIdx.x;

  if (blk < XBLKS) {
    const float4* x4 = reinterpret_cast<const float4*>(x);
    for (int idx = blk * 256 + tid; idx < BT_*D_/8; idx += XBLKS * 256) {
      float4 a = x4[idx*2], b = x4[idx*2+1];
      short8 o;
      o[0] = (short)bf16bits(a.x); o[1] = (short)bf16bits(a.y);
      o[2] = (short)bf16bits(a.z); o[3] = (short)bf16bits(a.w);
      o[4] = (short)bf16bits(b.x); o[5] = (short)bf16bits(b.y);
      o[6] = (short)bf16bits(b.z); o[7] = (short)bf16bits(b.w);
      *reinterpret_cast<short8*>(&xb[idx*8]) = o;
    }
    return;
  }

  // weight transpose: source (K=512, N) row-major -> dest (N, K=512) bf16
  int wb = blk - XBLKS;
  const float* src;
  u16* dst;
  int srcld, k0, n0;
  if (wb < 192) {                 // wqkv: 8 K-tiles x 24 N-tiles
    src = wqkv; dst = wqkvT; srcld = N3D_;
    k0 = (wb & 7) * 64; n0 = (wb >> 3) * 64;
  } else {                        // wout: 8 x 8
    wb -= 192;
    src = wout; dst = woutT; srcld = D_;
    k0 = (wb & 7) * 64; n0 = (wb >> 3) * 64;
  }
  {
    int c = tid & 63, r0 = tid >> 6;
#pragma unroll
    for (int i = 0; i < 16; ++i) {
      int r = r0 * 16 + i;
      lt[r * 72 + c] = bf16bits(src[(long)(k0 + r) * srcld + n0 + c]);
    }
  }
  __syncthreads();
  {
    int kc = (tid & 7) * 8;
#pragma unroll
    for (int half = 0; half < 2; ++half) {
      int n = (tid >> 3) + half * 32;
      short8 v;
#pragma unroll
      for (int j = 0; j < 8; ++j) v[j] = (short)lt[(kc + j) * 72 + n];
      *reinterpret_cast<short8*>(&dst[(long)(n0 + n) * D_ + k0 + kc]) = v;
    }
  }
}

// ---------------------------------------------------------------------------
// GEMM (r13): C[M=8192][N] = A[M][512] * Wt[N][512]^T  (bf16, K=512, BK=64)
// 128x128 tile, 4 waves, 2-phase pipelined loop (dbuf LDS, stage-before-
// compute, vmcnt(0)+s_barrier per K-step). XCD-chunked swizzle.
// MODE 0: N=1536, epilogue LDS re-tile -> coalesced q/k/v^T stores.
// MODE 1: N=512, epilogue bias + row mask, f32 stores.
// ---------------------------------------------------------------------------
template <int MODE>
__global__ __launch_bounds__(256) void gemm_kernel(
    const u16* __restrict__ A, const u16* __restrict__ Wt,
    u16* __restrict__ qbuf, u16* __restrict__ kbuf, u16* __restrict__ vtbuf,
    const float* __restrict__ bias, const float* __restrict__ msk,
    float* __restrict__ out) {
  const int NBN = (MODE == 0) ? 12 : 4;
  // XCD-chunked bijective swizzle (nwg % 8 == 0)
  const int lin = blockIdx.x;
  const int cpx = gridDim.x >> 3;
  const int nn = (lin & 7) * cpx + (lin >> 3);
  const int bm = nn / NBN, bn = nn % NBN;

  const int tid = threadIdx.x;
  const int w = tid >> 6, l = tid & 63;
  const int wr = w >> 1, wc = w & 1;
  const int lr = l & 15, lg = l >> 4;
  const int srow = l >> 3;
  const int scol = ((l & 7) ^ srow) << 4;

  __shared__ char ls[2][32768];     // [dbuf][ A 16K | B 16K ]

  f32x4 acc[4][4];
#pragma unroll
  for (int i = 0; i < 4; ++i)
#pragma unroll
    for (int j = 0; j < 4; ++j) acc[i][j] = fzero();

  const char* Ab = reinterpret_cast<const char*>(A) + (long)bm * 128 * 1024;
  const char* Wb = reinterpret_cast<const char*>(Wt) + (long)bn * 128 * 1024;

  auto stage = [&](int kt, char* dst) {
#pragma unroll
    for (int c = 0; c < 4; ++c) {
      int chunk = w * 4 + c;              // 0..15, wave-uniform
      int row = chunk * 8 + srow;         // 0..127
      gld_lds16(Ab + (long)row * 1024 + kt * 128 + scol, dst + chunk * 1024);
      gld_lds16(Wb + (long)row * 1024 + kt * 128 + scol, dst + 16384 + chunk * 1024);
    }
  };

  // prologue: first tile must fully land
  stage(0, ls[0]);
  asm volatile("s_waitcnt vmcnt(0)" ::: "memory");
  __builtin_amdgcn_s_barrier();

  int cur = 0;
  for (int kt = 0; kt < 8; ++kt) {
    if (kt + 1 < 8) stage(kt + 1, ls[cur ^ 1]);   // DMA flies during MFMAs
    const char* lsA = ls[cur];
    const char* lsB = ls[cur] + 16384;

#pragma unroll
    for (int c = 0; c < 2; ++c) {
      short8 af[4], bfr[4];
#pragma unroll
      for (int mi = 0; mi < 4; ++mi) {
        int row = wr * 64 + mi * 16 + lr;
        af[mi] = *reinterpret_cast<const short8*>(
            lsA + swz(row * 128 + c * 64 + lg * 16));
      }
#pragma unroll
      for (int ni = 0; ni < 4; ++ni) {
        int row = wc * 64 + ni * 16 + lr;
        bfr[ni] = *reinterpret_cast<const short8*>(
            lsB + swz(row * 128 + c * 64 + lg * 16));
      }
      __builtin_amdgcn_s_setprio(1);
#pragma unroll
      for (int mi = 0; mi < 4; ++mi)
#pragma unroll
        for (int ni = 0; ni < 4; ++ni)
          acc[mi][ni] = mfma16(af[mi], bfr[ni], acc[mi][ni]);
      __builtin_amdgcn_s_setprio(0);
    }

    asm volatile("s_waitcnt vmcnt(0)" ::: "memory");
    __builtin_amdgcn_s_barrier();
    cur ^= 1;
  }

  if (MODE == 0) {
    // ---- LDS re-tile epilogue (coalesced stores), uses ls[0] (32KB) ----
    char* lse = &ls[0][0];
    const int which = bn >> 2;            // 0=q 1=k 2=v^T
    if (which == 2) {
#pragma unroll
      for (int mi = 0; mi < 4; ++mi)
#pragma unroll
        for (int r = 0; r < 4; ++r) {
          int trow = wr * 64 + mi * 16 + lg * 4 + r;
#pragma unroll
          for (int ni = 0; ni < 4; ++ni) {
            int dcol = wc * 64 + ni * 16 + lr;
            int off = dcol * 256 + trow * 2;
            off ^= ((off >> 8) & 7) << 4;
            *reinterpret_cast<u16*>(lse + off) = bf16bits(acc[mi][ni][r]);
          }
        }
    } else {
      const float scale = (which == 0) ? QSCALE_F : 1.0f;
#pragma unroll
      for (int mi = 0; mi < 4; ++mi)
#pragma unroll
        for (int r = 0; r < 4; ++r) {
          int trow = wr * 64 + mi * 16 + lg * 4 + r;
#pragma unroll
          for (int ni = 0; ni < 4; ++ni) {
            int dcol = wc * 64 + ni * 16 + lr;
            int off = trow * 256 + dcol * 2;
            off ^= ((off >> 8) & 7) << 4;
            *reinterpret_cast<u16*>(lse + off) = bf16bits(acc[mi][ni][r] * scale);
          }
        }
    }
    __syncthreads();
    const int b = bm >> 4;                // T = 2048 = 16 * 128
    const int tb0 = (bm & 15) * 128;
    if (which == 2) {
      const int bn8 = bn - 8;
#pragma unroll
      for (int it = 0; it < 8; ++it) {
        int dp = it * 16 + (tid >> 4);    // d' 0..127
        int tc = (tid & 15) * 16;         // byte col within 256B row
        int off = dp * 256 + (tc ^ ((dp & 7) << 4));
        short8 v = *reinterpret_cast<const short8*>(lse + off);
        int h = 2 * bn8 + (dp >> 6), d = dp & 63;
        long dst = ((long)((b * H_ + h) * DH_ + d)) * T_ + tb0 + tc / 2;
        *reinterpret_cast<short8*>(vtbuf + dst) = v;
      }
    } else {
      u16* obuf = (which == 0) ? qbuf : kbuf;
#pragma unroll
      for (int it = 0; it < 8; ++it) {
        int trow = it * 16 + (tid >> 4);
        int tc = (tid & 15) * 16;
        int off = trow * 256 + (tc ^ ((trow & 7) << 4));
        short8 v = *reinterpret_cast<const short8*>(lse + off);
        int dcol = tc / 2;
        int h = (bn & 3) * 2 + (dcol >> 6), d = dcol & 63;
        long dst = ((long)(b * H_ + h) * T_ + tb0 + trow) * DH_ + d;
        *reinterpret_cast<short8*>(obuf + dst) = v;
      }
    }
  } else {
    // MODE 1: bias + row-mask, f32 coalesced stores
#pragma unroll
    for (int mi = 0; mi < 4; ++mi) {
#pragma unroll
      for (int r = 0; r < 4; ++r) {
        int grow = bm * 128 + wr * 64 + mi * 16 + lg * 4 + r;
#pragma unroll
        for (int ni = 0; ni < 4; ++ni) {
          int gcol = bn * 128 + wc * 64 + ni * 16 + lr;
          float o = (acc[mi][ni][r] + bias[gcol]) * msk[grow];
          out[(long)grow * D_ + gcol] = o;
        }
      }
    }
  }
}

// ---------------------------------------------------------------------------
// Flash attention, LDS-amortized: QBLK=128/block, 8 waves = wq[0,4) x hf{0,1}.
// Each wave owns 32 q-rows (2 subs x 16) of the 128-row q-tile; per KV tile
// the 8 K-frag reads and 8 V-frag reads are SHARED across both subs (K/V are
// q-independent) -> ~36% fewer LDS-pipe cycles per tile-unit (attn is
// LDS-pipe-throughput-bound: ~262 cyc/unit of ds ops vs ~80 MFMA).
// Same 80KB LDS / 2 blocks-per-CU shape as r13; kt<=qtw guard skips
// causally-dead sub-tiles so total work is unchanged.
// ---------------------------------------------------------------------------
__global__ __launch_bounds__(512, 4) void attn_kernel(
    const u16* __restrict__ q, const u16* __restrict__ k,
    const u16* __restrict__ vt, const float* __restrict__ msk,
    u16* __restrict__ ao) {
  const int bh = blockIdx.x;              // 0..31
  const int qt = 15 - blockIdx.y;         // 128-row q-tile, biggest first
  const int b = bh >> 3, h = bh & 7;
  const int tid = threadIdx.x;
  const int w = tid >> 6;                 // 0..7
  const int wq = w & 3;                   // 32-row group within the q-tile
  const int hf = w >> 2;                  // kv half
  const int l = tid & 63;
  const int lr = l & 15, lg = l >> 4;

  const float* mrow = msk + b * T_;

  unsigned long long bal = __ballot((l < 32) ? (mrow[l * 64] != 0.f) : false);
  const int nvalid = __popcll(bal);
  if (2 * qt >= nvalid) return;           // whole q-tile masked
  int nkv = 2 * qt + 2; if (nkv > nvalid) nkv = nvalid;
  const int nh = (nkv - hf + 1) >> 1;     // tiles for this half
  const int niter = (nkv + 1) >> 1;       // block-wide iterations

  __shared__ char lsK[2 * 2 * 8192];      // [half][dbuf][8KB] = 32KB
  __shared__ char lsV[2 * 2 * 8192];      // 32KB
  __shared__ char lsP[8 * 2048];          // 16KB, per-wave, reused per sub
  char* pbase = lsP + w * 2048;
  char* myK = lsK + hf * 16384;
  char* myV = lsV + hf * 16384;

  const char* kb = reinterpret_cast<const char*>(k)  + (long)bh * T_ * 128;
  const char* vb = reinterpret_cast<const char*>(vt) + (long)bh * DH_ * T_ * 2;
  const char* qb = reinterpret_cast<const char*>(q);

  const int qrow0 = qt * 128 + wq * 32;   // sub s rows: qrow0 + s*16 ..
  const int qtw = 2 * qt + (wq >> 1);     // wave's 64-row causal tile index

  // Q fragments: 2 subs x 2 k-chunks
  short8 qf[2][2];
#pragma unroll
  for (int s = 0; s < 2; ++s)
#pragma unroll
    for (int c = 0; c < 2; ++c)
      qf[s][c] = *reinterpret_cast<const short8*>(
          qb + (((long)bh * T_ + qrow0 + s * 16 + lr) * DH_ + c * 32 + lg * 8) * 2);

  const int srow = l >> 3;
  const int scol = ((l & 7) ^ srow) << 4;

  auto issue = [&](int kt_, int buf) {
#pragma unroll
    for (int c = 0; c < 2; ++c) {
      int chunk = wq * 2 + c;             // 0..7, wave-uniform
      int row = chunk * 8 + srow;         // 0..63
      gld_lds16(kb + ((long)kt_ * 64 + row) * 128 + scol,
                myK + buf * 8192 + chunk * 1024);
      gld_lds16(vb + (long)row * (T_ * 2) + kt_ * 128 + scol,
                myV + buf * 8192 + chunk * 1024);
    }
  };

  if (0 < nh) issue(hf, 0);

  float mrun[2] = {-__builtin_inff(), -__builtin_inff()};
  float lrun[2] = {0.f, 0.f};
  f32x4 oacc0[4], oacc1[4];               // static names (rule 20)
#pragma unroll
  for (int g = 0; g < 4; ++g) { oacc0[g] = fzero(); oacc1[g] = fzero(); }

  for (int i = 0; i < niter; ++i) {
    __syncthreads();                      // drains DMA + block sync
    if (i + 1 < nh) issue(2 * (i + 1) + hf, (i + 1) & 1);
    const int kt = 2 * i + hf;
    if (i < nh && kt <= qtw) {            // wave-uniform causal skip
      const char* lk = myK + (i & 1) * 8192;
      const char* lv = myV + (i & 1) * 8192;

      // QK^T for both subs: K-frag reads SHARED
      f32x4 st[2][4];
      __builtin_amdgcn_s_setprio(1);
#pragma unroll
      for (int ni = 0; ni < 4; ++ni) {
        short8 kf0 = *reinterpret_cast<const short8*>(
            lk + swz((ni * 16 + lr) * 128 + lg * 16));
        short8 kf1 = *reinterpret_cast<const short8*>(
            lk + swz((ni * 16 + lr) * 128 + 64 + lg * 16));
#pragma unroll
        for (int s = 0; s < 2; ++s) {
          f32x4 z = fzero();
          z = mfma16(kf0, qf[s][0], z);
          z = mfma16(kf1, qf[s][1], z);
          st[s][ni] = z;
        }
      }
      __builtin_amdgcn_s_setprio(0);

      const bool diag = (kt == qtw);
      const bool needcm = (mrow[kt * 64 + 63] == 0.f);
      if (diag || needcm) {
#pragma unroll
        for (int s = 0; s < 2; ++s)
#pragma unroll
          for (int ni = 0; ni < 4; ++ni)
#pragma unroll
            for (int r = 0; r < 4; ++r) {
              int jin = ni * 16 + lg * 4 + r;
              bool bad = (diag && jin > (wq & 1) * 32 + s * 16 + lr) ||
                         (needcm && mrow[kt * 64 + jin] == 0.f);
              if (bad) st[s][ni][r] = -3.402823466e38f;
            }
      }

      // per-sub softmax + P pack; P LDS reused (same-wave DS ops in-order);
      // pa frags held in regs so the PV loop can share V reads.
      short8 pa[2][2];
#pragma unroll
      for (int s = 0; s < 2; ++s) {
        float pmax = -3.402823466e38f;
#pragma unroll
        for (int ni = 0; ni < 4; ++ni)
#pragma unroll
          for (int r = 0; r < 4; ++r) pmax = fmaxf(pmax, st[s][ni][r]);
        pmax = fmaxf(pmax, __shfl_xor(pmax, 16));
        pmax = fmaxf(pmax, __shfl_xor(pmax, 32));

        if (!__all(pmax - mrun[s] <= 8.f)) {   // defer-max (T13)
          float newm = fmaxf(mrun[s], pmax);
          float alpha = fastexp(mrun[s] - newm);
          lrun[s] *= alpha;
          mrun[s] = newm;
#pragma unroll
          for (int rr = 0; rr < 4; ++rr) {
            float a = __shfl(alpha, lg * 4 + rr, 16);
            if (s == 0) {
#pragma unroll
              for (int g = 0; g < 4; ++g) oacc0[g][rr] *= a;
            } else {
#pragma unroll
              for (int g = 0; g < 4; ++g) oacc1[g][rr] *= a;
            }
          }
        }

        float p[4][4];
        float rs = 0.f;
#pragma unroll
        for (int ni = 0; ni < 4; ++ni)
#pragma unroll
          for (int r = 0; r < 4; ++r) {
            float pv = fastexp(st[s][ni][r] - mrun[s]);
            p[ni][r] = pv;
            rs += pv;
          }
        rs += __shfl_xor(rs, 16);
        rs += __shfl_xor(rs, 32);
        lrun[s] += rs;

#pragma unroll
        for (int ni = 0; ni < 4; ++ni)
#pragma unroll
          for (int rp = 0; rp < 2; ++rp) {
            unsigned lo = bf16bits(p[ni][2 * rp]);
            unsigned hi = bf16bits(p[ni][2 * rp + 1]);
            *reinterpret_cast<unsigned*>(
                pbase + swz(lr * 128 + ni * 32 + lg * 8 + rp * 4)) =
                lo | (hi << 16);
          }
        asm volatile("s_waitcnt lgkmcnt(0)" ::: "memory");
        pa[s][0] = *reinterpret_cast<const short8*>(
            pbase + swz(lr * 128 + lg * 16));
        pa[s][1] = *reinterpret_cast<const short8*>(
            pbase + swz(lr * 128 + 64 + lg * 16));
        asm volatile("s_waitcnt lgkmcnt(0)" ::: "memory");
      }

      // PV for both subs: V-frag reads SHARED
      __builtin_amdgcn_s_setprio(1);
#pragma unroll
      for (int c = 0; c < 2; ++c) {
#pragma unroll
        for (int g = 0; g < 4; ++g) {
          short8 vf = *reinterpret_cast<const short8*>(
              lv + swz((g * 16 + lr) * 128 + c * 64 + lg * 16));
          oacc0[g] = mfma16(pa[0][c], vf, oacc0[g]);
          oacc1[g] = mfma16(pa[1][c], vf, oacc1[g]);
        }
      }
      __builtin_amdgcn_s_setprio(0);
    }
  }

  // ---- merge the two KV-half partials per (wq, sub) via LDS ----
  __syncthreads();                        // all compute + DMA retired
  float* mO  = reinterpret_cast<float*>(lsK);   // [wq*2+s][16 q][64 d] = 32KB
  float* mML = reinterpret_cast<float*>(lsV);   // [wq*2+s][16 q][2]
  if (hf == 1) {
#pragma unroll
    for (int s = 0; s < 2; ++s) {
      int gi = wq * 2 + s;
#pragma unroll
      for (int g = 0; g < 4; ++g)
#pragma unroll
        for (int rr = 0; rr < 4; ++rr)
          mO[gi * 1024 + (lg * 4 + rr) * 64 + g * 16 + lr] =
              (s ? oacc1[g][rr] : oacc0[g][rr]);
      if (lg == 0) {
        mML[gi * 32 + lr * 2]     = mrun[s];
        mML[gi * 32 + lr * 2 + 1] = lrun[s];
      }
    }
  }
  __syncthreads();
  if (hf == 0) {
#pragma unroll
    for (int s = 0; s < 2; ++s) {
      int gi = wq * 2 + s;
      float m1 = mML[gi * 32 + lr * 2];
      float l1 = mML[gi * 32 + lr * 2 + 1];
      float M  = fmaxf(mrun[s], m1);      // mrun[s] (hf=0) always finite
      float a0 = fastexp(mrun[s] - M);
      float a1 = fastexp(m1 - M);         // exp(-inf)=0 when half empty
      float L  = a0 * lrun[s] + a1 * l1;
#pragma unroll
      for (int rr = 0; rr < 4; ++rr) {
        int qrow = lg * 4 + rr;
        float a0r = __shfl(a0, qrow, 16);
        float a1r = __shfl(a1, qrow, 16);
        float Lr  = __shfl(L,  qrow, 16);
        float inv = 1.0f / Lr;
        int t = qrow0 + s * 16 + qrow;
#pragma unroll
        for (int g = 0; g < 4; ++g) {
          float o = a0r * (s ? oacc1[g][rr] : oacc0[g][rr]) +
                    a1r * mO[gi * 1024 + qrow * 64 + g * 16 + lr];
          ao[((long)(b * T_ + t)) * D_ + h * 64 + g * 16 + lr] =
              bf16bits(o * inv);
        }
      }
    }
  }
}

// ---------------------------------------------------------------------------
extern "C" void kernel_launch(void* const* d_in, const int* in_sizes, int n_in,
                              void* d_out, int out_size, void* d_ws,
                              size_t ws_size, hipStream_t stream) {
  const float* x    = (const float*)d_in[0];
  const float* msk  = (const float*)d_in[1];   // (B,T,1)
  const float* wqkv = (const float*)d_in[2];   // (512,1536)
  const float* wout = (const float*)d_in[3];   // (512,512)
  const float* bout = (const float*)d_in[4];   // (512,)
  float* out = (float*)d_out;

  char* ws = (char*)d_ws;
  u16* xb    = (u16*)(ws);                     //  8 MB  x bf16 (8192,512)
  u16* wqkvT = (u16*)(ws + 8388608);           //  1.5MB (1536,512)
  u16* woutT = (u16*)(ws + 9961472);           //  0.5MB (512,512)
  u16* qbuf  = (u16*)(ws + 10485760);          //  8 MB  (B,H,T,DH) scaled
  u16* kbuf  = (u16*)(ws + 18874368);          //  8 MB  (B,H,T,DH)
  u16* vtbuf = (u16*)(ws + 27262976);          //  8 MB  (B,H,DH,T)
  u16* ao    = (u16*)(ws + 35651584);          //  8 MB  (B,T,D)

  prep_kernel<<<1024, 256, 0, stream>>>(x, wqkv, wout, xb, wqkvT, woutT);
  gemm_kernel<0><<<(N3D_ / 128) * (BT_ / 128), 256, 0, stream>>>(
      xb, wqkvT, qbuf, kbuf, vtbuf, nullptr, nullptr, nullptr);
  attn_kernel<<<dim3(B_ * H_, T_ / 128), 512, 0, stream>>>(
      qbuf, kbuf, vtbuf, msk, ao);
  gemm_kernel<1><<<(D_ / 128) * (BT_ / 128), 256, 0, stream>>>(
      ao, woutT, nullptr, nullptr, nullptr, bout, msk, out);
}

// Round 18
// 70.501 us; speedup vs baseline: 1.2185x; 1.2185x over previous
//
#include <hip/hip_runtime.h>
#include <hip/hip_bf16.h>

// Problem sizes (fixed by reference)
#define B_   4
#define T_   2048
#define D_   512
#define H_   8
#define DH_  64
#define BT_  (B_*T_)          // 8192
#define N3D_ (3*D_)           // 1536

typedef __bf16  bf16x8 __attribute__((ext_vector_type(8)));
typedef float   f32x4  __attribute__((ext_vector_type(4)));
typedef short   short8 __attribute__((ext_vector_type(8)));
typedef unsigned short u16;

// exp2 fast path: fold log2(e) into the Q scale so softmax uses v_exp_f32.
#if defined(__has_builtin)
#if __has_builtin(__builtin_amdgcn_exp2f)
#define EXP2_OK 1
#endif
#endif
#ifndef EXP2_OK
#define EXP2_OK 0
#endif

#if EXP2_OK
#define QSCALE_F (0.125f * 1.44269504088896340736f)
static __device__ __forceinline__ float fastexp(float x) { return __builtin_amdgcn_exp2f(x); }
#else
#define QSCALE_F (0.125f)
static __device__ __forceinline__ float fastexp(float x) { return __expf(x); }
#endif

static __device__ __forceinline__ f32x4 fzero() { f32x4 z = {0.f,0.f,0.f,0.f}; return z; }

static __device__ __forceinline__ f32x4 mfma16(short8 a, short8 b, f32x4 c) {
  return __builtin_amdgcn_mfma_f32_16x16x32_bf16(
      __builtin_bit_cast(bf16x8, a), __builtin_bit_cast(bf16x8, b), c, 0, 0, 0);
}

// XOR swizzle for [row][128B] LDS tiles (read side). Content is written
// pre-swizzled via the global SOURCE address (rule 21: linear DMA dest +
// inverse-swizzled source + swizzled read).
static __device__ __forceinline__ int swz(int byteoff) {
  return byteoff ^ (((byteoff >> 7) & 7) << 4);
}

static __device__ __forceinline__ u16 bf16bits(float f) {
  __hip_bfloat16 h = __float2bfloat16(f);
  return *reinterpret_cast<u16*>(&h);
}

// async global->LDS DMA, 16B per lane. lds dest must be wave-uniform base
// (HW writes base + lane*16); global src is per-lane.
static __device__ __forceinline__ void gld_lds16(const void* g, void* l) {
  __builtin_amdgcn_global_load_lds(
      (const __attribute__((address_space(1))) void*)g,
      (__attribute__((address_space(3))) void*)l, 16, 0, 0);
}

// ---------------------------------------------------------------------------
// Kernel 1 (fused prep): blocks [0,768): x -> bf16 (vectorized x8);
// blocks [768,960): wqkv LDS-tile transpose; [960,1024): wout transpose.
// ---------------------------------------------------------------------------
#define XBLKS 768
__global__ __launch_bounds__(256) void prep_kernel(
    const float* __restrict__ x, const float* __restrict__ wqkv,
    const float* __restrict__ wout,
    u16* __restrict__ xb, u16* __restrict__ wqkvT, u16* __restrict__ woutT) {
  __shared__ u16 lt[64 * 72];  // 64x64 bf16 tile, padded row stride 72
  const int tid = threadIdx.x;
  const int blk = blockIdx.x;

  if (blk < XBLKS) {
    const float4* x4 = reinterpret_cast<const float4*>(x);
    for (int idx = blk * 256 + tid; idx < BT_*D_/8; idx += XBLKS * 256) {
      float4 a = x4[idx*2], b = x4[idx*2+1];
      short8 o;
      o[0] = (short)bf16bits(a.x); o[1] = (short)bf16bits(a.y);
      o[2] = (short)bf16bits(a.z); o[3] = (short)bf16bits(a.w);
      o[4] = (short)bf16bits(b.x); o[5] = (short)bf16bits(b.y);
      o[6] = (short)bf16bits(b.z); o[7] = (short)bf16bits(b.w);
      *reinterpret_cast<short8*>(&xb[idx*8]) = o;
    }
    return;
  }

  // weight transpose: source (K=512, N) row-major -> dest (N, K=512) bf16
  int wb = blk - XBLKS;
  const float* src;
  u16* dst;
  int srcld, k0, n0;
  if (wb < 192) {                 // wqkv: 8 K-tiles x 24 N-tiles
    src = wqkv; dst = wqkvT; srcld = N3D_;
    k0 = (wb & 7) * 64; n0 = (wb >> 3) * 64;
  } else {                        // wout: 8 x 8
    wb -= 192;
    src = wout; dst = woutT; srcld = D_;
    k0 = (wb & 7) * 64; n0 = (wb >> 3) * 64;
  }
  {
    int c = tid & 63, r0 = tid >> 6;
#pragma unroll
    for (int i = 0; i < 16; ++i) {
      int r = r0 * 16 + i;
      lt[r * 72 + c] = bf16bits(src[(long)(k0 + r) * srcld + n0 + c]);
    }
  }
  __syncthreads();
  {
    int kc = (tid & 7) * 8;
#pragma unroll
    for (int half = 0; half < 2; ++half) {
      int n = (tid >> 3) + half * 32;
      short8 v;
#pragma unroll
      for (int j = 0; j < 8; ++j) v[j] = (short)lt[(kc + j) * 72 + n];
      *reinterpret_cast<short8*>(&dst[(long)(n0 + n) * D_ + k0 + kc]) = v;
    }
  }
}

// ---------------------------------------------------------------------------
// GEMM: C[M=8192][N] = A[M][512] * Wt[N][512]^T  (bf16, K=512, BK=64)
// 128x128 tile, 4 waves (64x64 quadrant, 4x4 frags). 2-phase pipelined loop:
// double-buffered LDS, stage(kt+1) issued BEFORE compute(kt), counted drain
// (vmcnt(0) AFTER the MFMAs) + one raw s_barrier per K-step (T3 minimum).
// 1-D grid with XCD-chunked swizzle (same-A-panel blocks share an XCD L2).
// MODE 0: N=1536. Each 128-col block is entirely q, k, or v (which = bn>>2).
//   Epilogue: LDS re-tile (transposed for v) -> coalesced short8 stores.
// MODE 1: N=512, epilogue adds bias, multiplies row mask, stores f32.
// ---------------------------------------------------------------------------
template <int MODE>
__global__ __launch_bounds__(256) void gemm_kernel(
    const u16* __restrict__ A, const u16* __restrict__ Wt,
    u16* __restrict__ qbuf, u16* __restrict__ kbuf, u16* __restrict__ vtbuf,
    const float* __restrict__ bias, const float* __restrict__ msk,
    float* __restrict__ out) {
  const int NBN = (MODE == 0) ? 12 : 4;
  // XCD-chunked bijective swizzle (nwg % 8 == 0)
  const int lin = blockIdx.x;
  const int cpx = gridDim.x >> 3;
  const int nn = (lin & 7) * cpx + (lin >> 3);
  const int bm = nn / NBN, bn = nn % NBN;

  const int tid = threadIdx.x;
  const int w = tid >> 6, l = tid & 63;
  const int wr = w >> 1, wc = w & 1;
  const int lr = l & 15, lg = l >> 4;
  const int srow = l >> 3;
  const int scol = ((l & 7) ^ srow) << 4;

  __shared__ char ls[2][32768];     // [dbuf][ A 16K | B 16K ]

  f32x4 acc[4][4];
#pragma unroll
  for (int i = 0; i < 4; ++i)
#pragma unroll
    for (int j = 0; j < 4; ++j) acc[i][j] = fzero();

  const char* Ab = reinterpret_cast<const char*>(A) + (long)bm * 128 * 1024;
  const char* Wb = reinterpret_cast<const char*>(Wt) + (long)bn * 128 * 1024;

  auto stage = [&](int kt, char* dst) {
#pragma unroll
    for (int c = 0; c < 4; ++c) {
      int chunk = w * 4 + c;              // 0..15, wave-uniform
      int row = chunk * 8 + srow;         // 0..127
      gld_lds16(Ab + (long)row * 1024 + kt * 128 + scol, dst + chunk * 1024);
      gld_lds16(Wb + (long)row * 1024 + kt * 128 + scol, dst + 16384 + chunk * 1024);
    }
  };

  // prologue: first tile must fully land
  stage(0, ls[0]);
  asm volatile("s_waitcnt vmcnt(0)" ::: "memory");
  __builtin_amdgcn_s_barrier();

  int cur = 0;
  for (int kt = 0; kt < 8; ++kt) {
    if (kt + 1 < 8) stage(kt + 1, ls[cur ^ 1]);   // DMA flies during MFMAs
    const char* lsA = ls[cur];
    const char* lsB = ls[cur] + 16384;

#pragma unroll
    for (int c = 0; c < 2; ++c) {
      short8 af[4], bfr[4];
#pragma unroll
      for (int mi = 0; mi < 4; ++mi) {
        int row = wr * 64 + mi * 16 + lr;
        af[mi] = *reinterpret_cast<const short8*>(
            lsA + swz(row * 128 + c * 64 + lg * 16));
      }
#pragma unroll
      for (int ni = 0; ni < 4; ++ni) {
        int row = wc * 64 + ni * 16 + lr;
        bfr[ni] = *reinterpret_cast<const short8*>(
            lsB + swz(row * 128 + c * 64 + lg * 16));
      }
      __builtin_amdgcn_s_setprio(1);
#pragma unroll
      for (int mi = 0; mi < 4; ++mi)
#pragma unroll
        for (int ni = 0; ni < 4; ++ni)
          acc[mi][ni] = mfma16(af[mi], bfr[ni], acc[mi][ni]);
      __builtin_amdgcn_s_setprio(0);
    }

    // drain next tile's DMA (latency already covered by the MFMAs above),
    // then one barrier: buf[cur^1] ready for all, buf[cur] reads done.
    asm volatile("s_waitcnt vmcnt(0)" ::: "memory");
    __builtin_amdgcn_s_barrier();
    cur ^= 1;
  }

  if (MODE == 0) {
    // ---- LDS re-tile epilogue (coalesced stores), uses ls[0] (32KB) ----
    char* lse = &ls[0][0];
    const int which = bn >> 2;            // 0=q 1=k 2=v^T
    if (which == 2) {
#pragma unroll
      for (int mi = 0; mi < 4; ++mi)
#pragma unroll
        for (int r = 0; r < 4; ++r) {
          int trow = wr * 64 + mi * 16 + lg * 4 + r;
#pragma unroll
          for (int ni = 0; ni < 4; ++ni) {
            int dcol = wc * 64 + ni * 16 + lr;
            int off = dcol * 256 + trow * 2;
            off ^= ((off >> 8) & 7) << 4;
            *reinterpret_cast<u16*>(lse + off) = bf16bits(acc[mi][ni][r]);
          }
        }
    } else {
      const float scale = (which == 0) ? QSCALE_F : 1.0f;
#pragma unroll
      for (int mi = 0; mi < 4; ++mi)
#pragma unroll
        for (int r = 0; r < 4; ++r) {
          int trow = wr * 64 + mi * 16 + lg * 4 + r;
#pragma unroll
          for (int ni = 0; ni < 4; ++ni) {
            int dcol = wc * 64 + ni * 16 + lr;
            int off = trow * 256 + dcol * 2;
            off ^= ((off >> 8) & 7) << 4;
            *reinterpret_cast<u16*>(lse + off) = bf16bits(acc[mi][ni][r] * scale);
          }
        }
    }
    __syncthreads();
    const int b = bm >> 4;                // T = 2048 = 16 * 128
    const int tb0 = (bm & 15) * 128;
    if (which == 2) {
      const int bn8 = bn - 8;
#pragma unroll
      for (int it = 0; it < 8; ++it) {
        int dp = it * 16 + (tid >> 4);    // d' 0..127
        int tc = (tid & 15) * 16;         // byte col within 256B row
        int off = dp * 256 + (tc ^ ((dp & 7) << 4));
        short8 v = *reinterpret_cast<const short8*>(lse + off);
        int h = 2 * bn8 + (dp >> 6), d = dp & 63;
        long dst = ((long)((b * H_ + h) * DH_ + d)) * T_ + tb0 + tc / 2;
        *reinterpret_cast<short8*>(vtbuf + dst) = v;
      }
    } else {
      u16* obuf = (which == 0) ? qbuf : kbuf;
#pragma unroll
      for (int it = 0; it < 8; ++it) {
        int trow = it * 16 + (tid >> 4);
        int tc = (tid & 15) * 16;
        int off = trow * 256 + (tc ^ ((trow & 7) << 4));
        short8 v = *reinterpret_cast<const short8*>(lse + off);
        int dcol = tc / 2;
        int h = (bn & 3) * 2 + (dcol >> 6), d = dcol & 63;
        long dst = ((long)(b * H_ + h) * T_ + tb0 + trow) * DH_ + d;
        *reinterpret_cast<short8*>(obuf + dst) = v;
      }
    }
  } else {
    // MODE 1: bias + row-mask, f32 coalesced stores
#pragma unroll
    for (int mi = 0; mi < 4; ++mi) {
#pragma unroll
      for (int r = 0; r < 4; ++r) {
        int grow = bm * 128 + wr * 64 + mi * 16 + lg * 4 + r;
#pragma unroll
        for (int ni = 0; ni < 4; ++ni) {
          int gcol = bn * 128 + wc * 64 + ni * 16 + lr;
          float o = (acc[mi][ni][r] + bias[gcol]) * msk[grow];
          out[(long)grow * D_ + gcol] = o;
        }
      }
    }
  }
}

// ---------------------------------------------------------------------------
// Flash attention, 8 waves: wave = (wq, hf). wq in [0,4): 16 q-rows each;
// hf in {0,1}: KV half, tiles kt = 2i+hf. Each half has its own
// double-buffered DMA-staged K/V LDS. Partials merged via LDS at the end.
// Grid (bh=32, qtslot=32); qt = 31 - qtslot so biggest blocks dispatch first.
// ---------------------------------------------------------------------------
__global__ __launch_bounds__(512) void attn_kernel(
    const u16* __restrict__ q, const u16* __restrict__ k,
    const u16* __restrict__ vt, const float* __restrict__ msk,
    u16* __restrict__ ao) {
  const int bh = blockIdx.x;              // 0..31
  const int qt = 31 - blockIdx.y;         // biggest first
  const int b = bh >> 3, h = bh & 7;
  const int tid = threadIdx.x;
  const int w = tid >> 6;                 // 0..7
  const int wq = w & 3;                   // q sub-tile
  const int hf = w >> 2;                  // kv half
  const int l = tid & 63;
  const int lr = l & 15, lg = l >> 4;

  const float* mrow = msk + b * T_;

  unsigned long long bal = __ballot((l < 32) ? (mrow[l * 64] != 0.f) : false);
  const int nvalid = __popcll(bal);
  if (qt >= nvalid) return;
  const int nkv = (qt + 1 < nvalid) ? (qt + 1) : nvalid;
  const int nh = (nkv - hf + 1) >> 1;     // tiles for this half
  const int niter = (nkv + 1) >> 1;       // block-wide iterations

  __shared__ char lsK[2 * 2 * 64 * 128];  // [half][dbuf][8KB] = 32KB
  __shared__ char lsV[2 * 2 * 64 * 128];  // 32KB
  __shared__ char lsP[8 * 16 * 128];      // 16KB
  char* pbase = lsP + w * (16 * 128);
  char* myK = lsK + hf * 16384;
  char* myV = lsV + hf * 16384;

  const char* kb = reinterpret_cast<const char*>(k)  + (long)bh * T_ * 128;
  const char* vb = reinterpret_cast<const char*>(vt) + (long)bh * DH_ * T_ * 2;
  const char* qb = reinterpret_cast<const char*>(q);

  const int qrow0 = qt * 64 + wq * 16;

  short8 qf[2];
#pragma unroll
  for (int c = 0; c < 2; ++c)
    qf[c] = *reinterpret_cast<const short8*>(
        qb + (((long)bh * T_ + qrow0 + lr) * DH_ + c * 32 + lg * 8) * 2);

  const int srow = l >> 3;
  const int scol = ((l & 7) ^ srow) << 4;

  auto issue = [&](int kt_, int buf) {
#pragma unroll
    for (int c = 0; c < 2; ++c) {
      int chunk = wq * 2 + c;             // 0..7, wave-uniform
      int row = chunk * 8 + srow;         // 0..63
      gld_lds16(kb + ((long)kt_ * 64 + row) * 128 + scol,
                myK + buf * 8192 + chunk * 1024);
      gld_lds16(vb + (long)row * (T_ * 2) + kt_ * 128 + scol,
                myV + buf * 8192 + chunk * 1024);
    }
  };

  if (0 < nh) issue(hf, 0);

  float mrun = -__builtin_inff(), lrun = 0.f;
  f32x4 oacc[4];
#pragma unroll
  for (int g = 0; g < 4; ++g) oacc[g] = fzero();

  for (int i = 0; i < niter; ++i) {
    __syncthreads();                      // drains DMA + block sync
    if (i + 1 < nh) issue(2 * (i + 1) + hf, (i + 1) & 1);
    if (i < nh) {
      const int kt = 2 * i + hf;
      const char* lk = myK + (i & 1) * 8192;
      const char* lv = myV + (i & 1) * 8192;

      f32x4 st[4];
      __builtin_amdgcn_s_setprio(1);
#pragma unroll
      for (int ni = 0; ni < 4; ++ni) {
        short8 kf0 = *reinterpret_cast<const short8*>(
            lk + swz((ni * 16 + lr) * 128 + lg * 16));
        short8 kf1 = *reinterpret_cast<const short8*>(
            lk + swz((ni * 16 + lr) * 128 + 64 + lg * 16));
        f32x4 z = fzero();
        z = mfma16(kf0, qf[0], z);
        z = mfma16(kf1, qf[1], z);
        st[ni] = z;
      }
      __builtin_amdgcn_s_setprio(0);

      const bool diag = (kt == qt);
      const bool needcm = (mrow[kt * 64 + 63] == 0.f);
      if (diag || needcm) {
#pragma unroll
        for (int ni = 0; ni < 4; ++ni)
#pragma unroll
          for (int r = 0; r < 4; ++r) {
            int jin = ni * 16 + lg * 4 + r;
            bool bad = (diag && jin > wq * 16 + lr) ||
                       (needcm && mrow[kt * 64 + jin] == 0.f);
            if (bad) st[ni][r] = -3.402823466e38f;
          }
      }

      float pmax = -3.402823466e38f;
#pragma unroll
      for (int ni = 0; ni < 4; ++ni)
#pragma unroll
        for (int r = 0; r < 4; ++r) pmax = fmaxf(pmax, st[ni][r]);
      pmax = fmaxf(pmax, __shfl_xor(pmax, 16));
      pmax = fmaxf(pmax, __shfl_xor(pmax, 32));

      if (!__all(pmax - mrun <= 8.f)) {   // defer-max (T13)
        float newm = fmaxf(mrun, pmax);
        float alpha = fastexp(mrun - newm);
        lrun *= alpha;
        mrun = newm;
#pragma unroll
        for (int rr = 0; rr < 4; ++rr) {
          float a = __shfl(alpha, lg * 4 + rr, 16);
#pragma unroll
          for (int g = 0; g < 4; ++g) oacc[g][rr] *= a;
        }
      }

      float p[4][4];
      float rs = 0.f;
#pragma unroll
      for (int ni = 0; ni < 4; ++ni)
#pragma unroll
        for (int r = 0; r < 4; ++r) {
          float pv = fastexp(st[ni][r] - mrun);
          p[ni][r] = pv;
          rs += pv;
        }
      rs += __shfl_xor(rs, 16);
      rs += __shfl_xor(rs, 32);
      lrun += rs;

#pragma unroll
      for (int ni = 0; ni < 4; ++ni)
#pragma unroll
        for (int rp = 0; rp < 2; ++rp) {
          unsigned lo = bf16bits(p[ni][2 * rp]);
          unsigned hi = bf16bits(p[ni][2 * rp + 1]);
          *reinterpret_cast<unsigned*>(
              pbase + swz(lr * 128 + ni * 32 + lg * 8 + rp * 4)) = lo | (hi << 16);
        }
      asm volatile("s_waitcnt lgkmcnt(0)" ::: "memory");

      __builtin_amdgcn_s_setprio(1);
#pragma unroll
      for (int c = 0; c < 2; ++c) {
        short8 pa = *reinterpret_cast<const short8*>(
            pbase + swz(lr * 128 + c * 64 + lg * 16));
#pragma unroll
        for (int g = 0; g < 4; ++g) {
          short8 vf = *reinterpret_cast<const short8*>(
              lv + swz((g * 16 + lr) * 128 + c * 64 + lg * 16));
          oacc[g] = mfma16(pa, vf, oacc[g]);
        }
      }
      __builtin_amdgcn_s_setprio(0);
    }
  }

  // ---- merge the two KV-half partials via LDS (reuse lsK region) ----
  __syncthreads();
  float* mO  = reinterpret_cast<float*>(lsK);            // [wq][16 q][64 d]
  float* mML = reinterpret_cast<float*>(lsK + 4 * 4096); // [wq][16 q][2]
  if (hf == 1) {
#pragma unroll
    for (int g = 0; g < 4; ++g)
#pragma unroll
      for (int rr = 0; rr < 4; ++rr)
        mO[wq * 1024 + (lg * 4 + rr) * 64 + g * 16 + lr] = oacc[g][rr];
    if (lg == 0) {
      mML[wq * 32 + lr * 2]     = mrun;
      mML[wq * 32 + lr * 2 + 1] = lrun;
    }
  }
  __syncthreads();
  if (hf == 0) {
    float m1 = mML[wq * 32 + lr * 2];
    float l1 = mML[wq * 32 + lr * 2 + 1];
    float M  = fmaxf(mrun, m1);
    float a0 = fastexp(mrun - M);
    float a1 = fastexp(m1 - M);
    float L  = a0 * lrun + a1 * l1;
#pragma unroll
    for (int rr = 0; rr < 4; ++rr) {
      int qrow = lg * 4 + rr;
      float a0r = __shfl(a0, qrow, 16);
      float a1r = __shfl(a1, qrow, 16);
      float Lr  = __shfl(L,  qrow, 16);
      float inv = 1.0f / Lr;
      int t = qrow0 + qrow;
#pragma unroll
      for (int g = 0; g < 4; ++g) {
        float o = a0r * oacc[g][rr] +
                  a1r * mO[wq * 1024 + qrow * 64 + g * 16 + lr];
        ao[((long)(b * T_ + t)) * D_ + h * 64 + g * 16 + lr] = bf16bits(o * inv);
      }
    }
  }
}

// ---------------------------------------------------------------------------
extern "C" void kernel_launch(void* const* d_in, const int* in_sizes, int n_in,
                              void* d_out, int out_size, void* d_ws,
                              size_t ws_size, hipStream_t stream) {
  const float* x    = (const float*)d_in[0];
  const float* msk  = (const float*)d_in[1];   // (B,T,1)
  const float* wqkv = (const float*)d_in[2];   // (512,1536)
  const float* wout = (const float*)d_in[3];   // (512,512)
  const float* bout = (const float*)d_in[4];   // (512,)
  float* out = (float*)d_out;

  char* ws = (char*)d_ws;
  u16* xb    = (u16*)(ws);                     //  8 MB  x bf16 (8192,512)
  u16* wqkvT = (u16*)(ws + 8388608);           //  1.5MB (1536,512)
  u16* woutT = (u16*)(ws + 9961472);           //  0.5MB (512,512)
  u16* qbuf  = (u16*)(ws + 10485760);          //  8 MB  (B,H,T,DH) scaled
  u16* kbuf  = (u16*)(ws + 18874368);          //  8 MB  (B,H,T,DH)
  u16* vtbuf = (u16*)(ws + 27262976);          //  8 MB  (B,H,DH,T)
  u16* ao    = (u16*)(ws + 35651584);          //  8 MB  (B,T,D)

  prep_kernel<<<1024, 256, 0, stream>>>(x, wqkv, wout, xb, wqkvT, woutT);
  gemm_kernel<0><<<(N3D_ / 128) * (BT_ / 128), 256, 0, stream>>>(
      xb, wqkvT, qbuf, kbuf, vtbuf, nullptr, nullptr, nullptr);
  attn_kernel<<<dim3(B_ * H_, T_ / 64), 512, 0, stream>>>(
      qbuf, kbuf, vtbuf, msk, ao);
  gemm_kernel<1><<<(D_ / 128) * (BT_ / 128), 256, 0, stream>>>(
      ao, woutT, nullptr, nullptr, nullptr, bout, msk, out);
}